// Round 3
// baseline (105.400 us; speedup 1.0000x reference)
//
#include <hip/hip_runtime.h>

#define BB 32
#define SS 2048
#define DD 1024

typedef float f32x4 __attribute__((ext_vector_type(4)));

#if defined(__has_builtin)
#  if __has_builtin(__builtin_amdgcn_exp2f)
#    define EXP2F(x) __builtin_amdgcn_exp2f(x)
#  endif
#  if __has_builtin(__builtin_amdgcn_rcpf)
#    define RCPF(x) __builtin_amdgcn_rcpf(x)
#  endif
#endif
#ifndef EXP2F
#  define EXP2F(x) exp2f(x)
#endif
#ifndef RCPF
#  define RCPF(x) (1.0f / (x))
#endif

#define LOG2E 1.44269504088896340736f

__device__ __forceinline__ float fast_tanh(float x) {
    x = fminf(fmaxf(x, -20.0f), 20.0f);
    float e = EXP2F(x * (2.0f * LOG2E));
    return (e - 1.0f) * RCPF(e + 1.0f);
}

__device__ __forceinline__ f32x4 ntload4(const float* p) {
    return __builtin_nontemporal_load((const f32x4*)p);
}

// ---------------- K1: dec_feature = dec_hidden @ W^T + b ----------------
// wave-per-output-column: wave holds W row i in regs (W read ONCE),
// loops 32 batches over L1/L2-resident dh. grid 256 x 256 (4 waves).
__global__ __launch_bounds__(256) void k_decfeat(
    const float* __restrict__ dh, const float* __restrict__ W,
    const float* __restrict__ bd, float* __restrict__ df) {
    int wave = threadIdx.x >> 6, lane = threadIdx.x & 63;
    int i = blockIdx.x * 4 + wave;          // 0..1023
    f32x4 w[4];
#pragma unroll
    for (int r = 0; r < 4; ++r)
        w[r] = ntload4(W + (size_t)i * DD + (lane + 64 * r) * 4);
    float bi = bd[i];
    for (int b = 0; b < BB; ++b) {
        const float* drow = dh + (size_t)b * DD;
        float acc = 0.0f;
#pragma unroll
        for (int r = 0; r < 4; ++r) {
            f32x4 d = *(const f32x4*)(drow + (lane + 64 * r) * 4);
            acc += w[r].x * d.x + w[r].y * d.y + w[r].z * d.z + w[r].w * d.w;
        }
#pragma unroll
        for (int off = 32; off; off >>= 1) acc += __shfl_down(acc, off, 64);
        if (lane == 0) df[(size_t)b * DD + i] = acc + bi;
    }
}

// ---------------- K2: E[b,s] = exp(v . tanh(ef + df + cov*wc)) ----------------
// no max-subtraction: |score| <= ||v||_1 (~26), exp2f safe in f32; the
// global softmax denominator cancels in the mask-renormalization.
__global__ __launch_bounds__(256) void k_score(
    const float* __restrict__ ef, const float* __restrict__ df,
    const float* __restrict__ cov, const float* __restrict__ v,
    const float* __restrict__ wc, float* __restrict__ E) {
    int b  = blockIdx.x >> 8;               // 256 tiles per batch
    int s0 = (blockIdx.x & 255) * 8;
    int t  = threadIdx.x;
    float4 v4 = ((const float4*)v)[t];
    float4 w4 = ((const float4*)wc)[t];
    float4 d4 = ((const float4*)(df + (size_t)b * DD))[t];
    float part[8];
#pragma unroll
    for (int k = 0; k < 8; ++k) {
        int s = s0 + k;
        float c = cov[b * SS + s];
        f32x4 e4 = ntload4(ef + ((size_t)b * SS + s) * DD + t * 4);
        float t0 = fast_tanh(e4.x + d4.x + c * w4.x);
        float t1 = fast_tanh(e4.y + d4.y + c * w4.y);
        float t2 = fast_tanh(e4.z + d4.z + c * w4.z);
        float t3 = fast_tanh(e4.w + d4.w + c * w4.w);
        part[k] = v4.x * t0 + v4.y * t1 + v4.z * t2 + v4.w * t3;
    }
    __shared__ float red[4][8];
    int lane = t & 63, wave = t >> 6;
#pragma unroll
    for (int k = 0; k < 8; ++k) {
        float p = part[k];
#pragma unroll
        for (int off = 32; off; off >>= 1) p += __shfl_down(p, off, 64);
        if (lane == 0) red[wave][k] = p;
    }
    __syncthreads();
    if (t < 8) {
        float sc = red[0][t] + red[1][t] + red[2][t] + red[3][t];
        E[b * SS + s0 + t] = EXP2F(sc * LOG2E);
    }
}

// ---------------- K3a: inv[b] = 1 / sum_s E*mask ----------------
__global__ __launch_bounds__(256) void k_sumexp(
    const float* __restrict__ E, const float* __restrict__ mask,
    float* __restrict__ inv) {
    int b = blockIdx.x, t = threadIdx.x;
    int lane = t & 63, wave = t >> 6;
    float sum = 0.0f;
#pragma unroll
    for (int k = 0; k < 8; ++k) {
        int s = t + 256 * k;
        sum += E[b * SS + s] * mask[b * SS + s];
    }
#pragma unroll
    for (int off = 32; off; off >>= 1) sum += __shfl_down(sum, off, 64);
    __shared__ float red[4];
    if (lane == 0) red[wave] = sum;
    __syncthreads();
    if (t == 0) inv[b] = 1.0f / (red[0] + red[1] + red[2] + red[3]);
}

// ---------------- K4: attn/covnew writes + context partials ----------------
// block = (b, 64-row chunk); prologue computes attn for its rows (writes
// attn & covnew), then streams enc_output accumulating partials.
__global__ __launch_bounds__(256) void k_ctx_part(
    const float* __restrict__ eo, const float* __restrict__ E,
    const float* __restrict__ mask, const float* __restrict__ cov,
    const float* __restrict__ inv, float* __restrict__ attn,
    float* __restrict__ covnew, float* __restrict__ part) {
    int b = blockIdx.x >> 5, ch = blockIdx.x & 31;
    int t = threadIdx.x;
    int s0 = ch * 64;
    __shared__ float als[64];
    if (t < 64) {
        int s = s0 + t;
        float a = E[b * SS + s] * mask[b * SS + s] * inv[b];
        attn[b * SS + s] = a;
        covnew[b * SS + s] = cov[b * SS + s] + a;
        als[t] = a;
    }
    __syncthreads();
    const float* base = eo + ((size_t)b * SS + s0) * DD;
    f32x4 acc = {0.f, 0.f, 0.f, 0.f};
#pragma unroll 8
    for (int k = 0; k < 64; ++k) {
        f32x4 e4 = ntload4(base + (size_t)k * DD + t * 4);
        acc += als[k] * e4;
    }
    ((f32x4*)part)[((size_t)b * 32 + ch) * 256 + t] = acc;
}

// ---------------- K5: reduce partials into context (256 blocks) ----------------
__global__ __launch_bounds__(256) void k_ctx_reduce(
    const float* __restrict__ part, float* __restrict__ ctx) {
    int b = blockIdx.x >> 3, dt = blockIdx.x & 7;
    int t = threadIdx.x;
    int slot = t & 31, grp = t >> 5;
    int f4 = dt * 32 + slot;
    const f32x4* p = (const f32x4*)part;
    f32x4 acc = {0.f, 0.f, 0.f, 0.f};
#pragma unroll
    for (int j = 0; j < 4; ++j) {
        int ch = grp + 8 * j;
        acc += p[((size_t)b * 32 + ch) * 256 + f4];
    }
    __shared__ f32x4 red[8][32];
    red[grp][slot] = acc;
    __syncthreads();
    if (t < 32) {
        f32x4 s = red[0][t];
#pragma unroll
        for (int g = 1; g < 8; ++g) s += red[g][t];
        ((f32x4*)ctx)[(size_t)b * 256 + dt * 32 + t] = s;
    }
}

extern "C" void kernel_launch(void* const* d_in, const int* in_sizes, int n_in,
                              void* d_out, int out_size, void* d_ws, size_t ws_size,
                              hipStream_t stream) {
    const float* dec_hidden  = (const float*)d_in[0];
    const float* enc_output  = (const float*)d_in[1];
    const float* enc_feature = (const float*)d_in[2];
    const float* enc_mask    = (const float*)d_in[3];
    // d_in[4] = sec_attn (unused by reference outputs)
    const float* coverage    = (const float*)d_in[5];
    const float* W_dec       = (const float*)d_in[6];
    const float* b_dec       = (const float*)d_in[7];
    const float* v           = (const float*)d_in[8];
    const float* w_cov       = (const float*)d_in[9];

    float* ctx    = (float*)d_out;                     // [B, DIM]   32768
    float* attn   = (float*)d_out + BB * DD;           // [B, S]     65536
    float* covnew = (float*)d_out + BB * DD + BB * SS; // [B, S]     65536

    char* ws = (char*)d_ws;
    float* df   = (float*)(ws);                        // 128 KiB
    float* E    = (float*)(ws + 131072);               // 256 KiB
    float* inv  = (float*)(ws + 131072 + 262144);      // 128 B (pad to 1 KiB)
    float* part = (float*)(ws + 131072 + 262144 + 1024); // 4 MiB

    k_decfeat   <<<256,   256, 0, stream>>>(dec_hidden, W_dec, b_dec, df);
    k_score     <<<8192,  256, 0, stream>>>(enc_feature, df, coverage, v, w_cov, E);
    k_sumexp    <<<BB,    256, 0, stream>>>(E, enc_mask, inv);
    k_ctx_part  <<<BB*32, 256, 0, stream>>>(enc_output, E, enc_mask, coverage, inv,
                                            attn, covnew, part);
    k_ctx_reduce<<<BB*8,  256, 0, stream>>>(part, ctx);
}